// Round 1
// 755.992 us; speedup vs baseline: 1.1469x; 1.1469x over previous
//
#include <hip/hip_runtime.h>

// SpectralConv2d DHT pipeline, B=CIN=COUT=64, H=W=128, M1=M2=32.
// Everything is per flat channel ch in [0,4096): pure elementwise in ch.
//
// Pipeline per channel (all scales folded into tables):
//   A : CS[n1][j] = x(128x128) . T1(128x64)         (cos|sin over n2)   [MFMA split-bf16]
//       Xc[i][k2] = T2t^T(64x256) . stack(CS)       (cas/16384)         [MFMA split-bf16]
//   B1: hat = T4t^T . stack(tile . T3)              (DHT32 of Xc crops and of w1/w2 tiles)
//   B2: Y = T4t^T . stack((Ahat*What) . T3)         (scale 1/64 folded into T6)
//   C : UV[r][k2] = sum_j Y[j][k2]*T5t[j][r]        (r<128: cos p, r>=128: sin p)
//       out[p][q] = sum_ms UVt[ms][p]*T6[ms][q]     (T6 = cas*s4)

#define OFF_T1   0        // [128][64]
#define OFF_T2T  8192     // [256][64]
#define OFF_T3   24576    // [32][64]
#define OFF_T4T  26624    // [64][32]
#define OFF_T5T  28672    // [64][256]
#define OFF_T6   45056    // [64][128]
#define OFF_XCY  53248    // [4096][64][32] (Xc, then Y in place)
#define WS_FLOATS (53248 + 4096 * 2048)

// bf16 MFMA fragment tables (hi/lo split), stored in d_out at +64MB:
//   T1frag: 4 ksteps x 4 ntiles x {hi,lo} x 64 lanes x 8 bf16 = 16384 ushorts (32KB)
//   T2frag: 4 mtiles x 8 ksteps x {hi,lo} x 64 lanes x 8 bf16 = 32768 ushorts (64KB)
#define TF_BYTE_OFF (64u << 20)

typedef __attribute__((ext_vector_type(8))) short bf16x8;
typedef __attribute__((ext_vector_type(4))) float f32x4;

__device__ __forceinline__ int kmap(int i) { return (i < 32) ? i : 64 + i; }

__device__ __forceinline__ unsigned short f2bf(float f) {
    unsigned int u = __float_as_uint(f);
    return (unsigned short)((u + 0x7fffu + ((u >> 16) & 1u)) >> 16);  // RNE
}
__device__ __forceinline__ float bf2f(unsigned short h) {
    return __uint_as_float(((unsigned int)h) << 16);
}

__device__ __forceinline__ void fma4(float* a, float s, float4 b) {
    a[0] = fmaf(s, b.x, a[0]); a[1] = fmaf(s, b.y, a[1]);
    a[2] = fmaf(s, b.z, a[2]); a[3] = fmaf(s, b.w, a[3]);
}

__global__ __launch_bounds__(256) void init_tables(float* ws) {
    int idx = blockIdx.x * 256 + threadIdx.x;
    if (idx >= 53248) return;
    const float w128 = 6.2831853071795864769f / 128.0f;
    const float w32  = 6.2831853071795864769f / 32.0f;
    if (idx < 8192) {                       // T1[n2][j]: j<32 cos(2pi j n2/128) else sin
        int n2 = idx >> 6, j = idx & 63, jj = j & 31;
        float a = w128 * (float)((jj * n2) & 127);
        ws[OFF_T1 + idx] = (j < 32) ? cosf(a) : sinf(a);
    } else if (idx < 24576) {               // T2t[m][i]
        int t = idx - 8192, m = t >> 6, i = t & 63;
        int k1 = kmap(i);
        float v;
        if (m < 128) { float a = w128 * (float)((k1 * m) & 127); v = cosf(a) + sinf(a); }
        else { int mm = m - 128; float a = w128 * (float)((k1 * mm) & 127); v = cosf(a) - sinf(a); }
        ws[OFF_T2T + t] = v * (1.0f / 16384.0f);
    } else if (idx < 26624) {               // T3[n2][j]
        int t = idx - 24576, n2 = t >> 6, j = t & 63, jj = j & 31;
        float a = w32 * (float)((jj * n2) & 31);
        ws[OFF_T3 + t] = (j < 32) ? cosf(a) : sinf(a);
    } else if (idx < 28672) {               // T4t[m][k1]
        int t = idx - 26624, m = t >> 5, k1 = t & 31;
        float v;
        if (m < 32) { float a = w32 * (float)((k1 * m) & 31); v = cosf(a) + sinf(a); }
        else { int mm = m - 32; float a = w32 * (float)((k1 * mm) & 31); v = cosf(a) - sinf(a); }
        ws[OFF_T4T + t] = v * (1.0f / 1024.0f);
    } else if (idx < 45056) {               // T5t[j][r]
        int t = idx - 28672, j = t >> 8, r = t & 255;
        int k1 = kmap(j);
        int p = (r < 128) ? r : r - 128;
        float a = w128 * (float)((p * k1) & 127);
        ws[OFF_T5T + t] = (r < 128) ? cosf(a) : sinf(a);
    } else {                                // T6[m][q]
        int t = idx - 45056, m = t >> 7, q = t & 127;
        int k2 = m & 31;
        float a = w128 * (float)((q * k2) & 127);
        float c = cosf(a), s = sinf(a);
        const float s4 = 1.0f / 67108864.0f;
        ws[OFF_T6 + t] = ((m < 32) ? (c + s) : (c - s)) * s4;
    }
}

// Fragment-linear bf16 hi/lo tables for kA's two MFMA GEMMs.
// MFMA 16x16x32 bf16 operand layout: A[l%16][8*(l/16)+i], B[8*(l/16)+i][l%16].
__global__ __launch_bounds__(256) void init_frag(unsigned short* tf) {
    int idx = blockIdx.x * 256 + threadIdx.x;
    if (idx >= 49152) return;
    const float w128 = 6.2831853071795864769f / 128.0f;
    float v;
    int hl;
    if (idx < 16384) {
        // T1frag: frag = ((ks*4+nt)*2+hl); B[k][n] = T1[n2 = ks*32+8*(l/16)+i][j = nt*16 + l%16]
        int frag = idx >> 9, lane = (idx >> 3) & 63, ii = idx & 7;
        hl = frag & 1;
        int nt = (frag >> 1) & 3, ks = frag >> 3;
        int n2 = ks * 32 + (lane >> 4) * 8 + ii;
        int j = nt * 16 + (lane & 15);
        int jj = j & 31;
        float a = w128 * (float)((jj * n2) & 127);
        v = (j < 32) ? cosf(a) : sinf(a);
    } else {
        // T2frag: frag = ((mt*8+ks)*2+hl); A[io][m] = T2t[m = ks*32+8*(l/16)+i][io = mt*16 + l%16]
        int t = idx - 16384;
        int frag = t >> 9, lane = (t >> 3) & 63, ii = t & 7;
        hl = frag & 1;
        int ks = (frag >> 1) & 7, mt = frag >> 4;
        int m = ks * 32 + (lane >> 4) * 8 + ii;
        int io = mt * 16 + (lane & 15);
        int k1 = kmap(io);
        if (m < 128) { float a = w128 * (float)((k1 * m) & 127); v = cosf(a) + sinf(a); }
        else { int mm = m - 128; float a = w128 * (float)((k1 * mm) & 127); v = cosf(a) - sinf(a); }
        v *= (1.0f / 16384.0f);
    }
    unsigned short h = f2bf(v);
    tf[idx] = hl ? f2bf(v - bf2f(h)) : h;
}

// ---------------- Kernel A: x -> Xc (per channel), MFMA split-bf16 ----------------
// Split scheme: a = ah + al (bf16 pair, 2^-18 relative), product = ah*bh + ah*bl + al*bh.
__global__ __launch_bounds__(256) void kA(const float* __restrict__ x, float* __restrict__ ws,
                                          const unsigned short* __restrict__ tf) {
    __shared__ unsigned short CSThi[64 * 136];  // CST[j][n1] = CS[n1][j], hi bf16, pitch 136
    __shared__ unsigned short CSTlo[64 * 136];
    const int tid  = threadIdx.x;
    const int lane = tid & 63;
    const int wv   = tid >> 6;           // 4 waves
    const int ch   = blockIdx.x;
    const float* xg = x + ch * 16384;
    const int lr = lane & 15;            // row-in-tile (A) / col-in-tile (B,C)
    const int lk = (lane >> 4) * 8;      // k-offset within 32-slice
    const int lq = (lane >> 4) * 4;      // C/D row group

    const bf16x8* t1f = (const bf16x8*)tf;            // 32 frags x 64 lanes
    const bf16x8* t2f = (const bf16x8*)tf + 32 * 64;  // 64 frags x 64 lanes

    const f32x4 zero4 = {0.f, 0.f, 0.f, 0.f};

    // phase 1: CS = x(128x128) . T1(128x64).  Wave wv owns rows [wv*32, wv*32+32).
    f32x4 acc[2][4];
#pragma unroll
    for (int mt = 0; mt < 2; mt++)
#pragma unroll
        for (int nt = 0; nt < 4; nt++) acc[mt][nt] = zero4;

#pragma unroll
    for (int ks = 0; ks < 4; ks++) {
        bf16x8 ah[2], al[2];
#pragma unroll
        for (int mt = 0; mt < 2; mt++) {
            const float* src = xg + (wv * 32 + mt * 16 + lr) * 128 + ks * 32 + lk;
            float4 u0 = *(const float4*)src;
            float4 u1 = *(const float4*)(src + 4);
            float av[8] = {u0.x, u0.y, u0.z, u0.w, u1.x, u1.y, u1.z, u1.w};
#pragma unroll
            for (int i = 0; i < 8; i++) {
                unsigned short h = f2bf(av[i]);
                ah[mt][i] = (short)h;
                al[mt][i] = (short)f2bf(av[i] - bf2f(h));
            }
        }
#pragma unroll
        for (int nt = 0; nt < 4; nt++) {
            bf16x8 bh = t1f[((ks * 4 + nt) * 2 + 0) * 64 + lane];
            bf16x8 bl = t1f[((ks * 4 + nt) * 2 + 1) * 64 + lane];
#pragma unroll
            for (int mt = 0; mt < 2; mt++) {
                acc[mt][nt] = __builtin_amdgcn_mfma_f32_16x16x32_bf16(ah[mt], bh, acc[mt][nt], 0, 0, 0);
                acc[mt][nt] = __builtin_amdgcn_mfma_f32_16x16x32_bf16(ah[mt], bl, acc[mt][nt], 0, 0, 0);
                acc[mt][nt] = __builtin_amdgcn_mfma_f32_16x16x32_bf16(al[mt], bh, acc[mt][nt], 0, 0, 0);
            }
        }
    }

    // CS -> CST in LDS as bf16 hi/lo pairs (transposed so phase-2 B-frags are ds_read_b128).
    // C/D layout: col = lane&15 (=j within tile), row = (lane>>4)*4 + r (=n1 within tile).
#pragma unroll
    for (int mt = 0; mt < 2; mt++)
#pragma unroll
        for (int nt = 0; nt < 4; nt++) {
            const int j  = nt * 16 + lr;
            const int n1 = wv * 32 + mt * 16 + lq;
            unsigned short h[4], lo[4];
#pragma unroll
            for (int r = 0; r < 4; r++) {
                float v = acc[mt][nt][r];
                h[r]  = f2bf(v);
                lo[r] = f2bf(v - bf2f(h[r]));
            }
            uint2 hv = make_uint2((unsigned int)h[0] | ((unsigned int)h[1] << 16),
                                  (unsigned int)h[2] | ((unsigned int)h[3] << 16));
            uint2 lv = make_uint2((unsigned int)lo[0] | ((unsigned int)lo[1] << 16),
                                  (unsigned int)lo[2] | ((unsigned int)lo[3] << 16));
            *(uint2*)&CSThi[j * 136 + n1] = hv;
            *(uint2*)&CSTlo[j * 136 + n1] = lv;
        }
    __syncthreads();

    // phase 2: Xc = A(64x256) . CSbig(256x32), A[i][m] = T2t[m][i].
    // CSbig[m][k2] = (m<128) ? CS[m][k2] : CS[m-128][32+k2]  ==  CST[k2 + 32*(m>=128)][m%128].
    // Wave wv owns M-tile wv (rows i in [wv*16, wv*16+16)).
    f32x4 a2[2] = {zero4, zero4};
#pragma unroll
    for (int ks = 0; ks < 8; ks++) {
        bf16x8 ah = t2f[((wv * 8 + ks) * 2 + 0) * 64 + lane];
        bf16x8 al = t2f[((wv * 8 + ks) * 2 + 1) * 64 + lane];
        const int colb = (ks & 3) * 32 + lk;       // m % 128 base (8 consecutive)
        const int rofs = (ks >= 4) ? 32 : 0;
#pragma unroll
        for (int nt = 0; nt < 2; nt++) {
            const int row = nt * 16 + lr + rofs;
            bf16x8 bh = *(const bf16x8*)&CSThi[row * 136 + colb];
            bf16x8 bl = *(const bf16x8*)&CSTlo[row * 136 + colb];
            a2[nt] = __builtin_amdgcn_mfma_f32_16x16x32_bf16(ah, bh, a2[nt], 0, 0, 0);
            a2[nt] = __builtin_amdgcn_mfma_f32_16x16x32_bf16(ah, bl, a2[nt], 0, 0, 0);
            a2[nt] = __builtin_amdgcn_mfma_f32_16x16x32_bf16(al, bh, a2[nt], 0, 0, 0);
        }
    }
    float* xcg = ws + OFF_XCY + ch * 2048;
#pragma unroll
    for (int nt = 0; nt < 2; nt++)
#pragma unroll
        for (int r = 0; r < 4; r++) {
            const int io = wv * 16 + lq + r;
            xcg[io * 32 + nt * 16 + lr] = a2[nt][r];
        }
}

// ---------------- Kernel B1: DHT32 of all Xc crops and w tiles ----------------
__global__ __launch_bounds__(128) void kB1(const float* __restrict__ w1, const float* __restrict__ w2,
                                           float* ws, float* wh) {
    __shared__ float inT[2304];  // [2][32][36] transposed inputs
    __shared__ float G[4352];    // [2][32][68]
    __shared__ float T3c[2048];
    __shared__ float T4c[2048];
    const int tid = threadIdx.x;
#pragma unroll
    for (int i = 0; i < 16; i++) {
        int t = i * 128 + tid;
        T3c[t] = ws[OFF_T3 + t];
        T4c[t] = ws[OFF_T4T + t];
    }
    float* dstp[2];
#pragma unroll
    for (int tt = 0; tt < 2; tt++) {
        int g = blockIdx.x * 2 + tt;
        const float* src; float* dst;
        if (g < 8192) {
            int ch = g >> 1, crop = g & 1;
            dst = ws + OFF_XCY + ch * 2048 + crop * 1024;
            src = dst;
        } else {
            int gw = g - 8192;
            int ch = gw >> 1, t2 = gw & 1;
            src = (t2 ? w2 : w1) + ch * 1024;
            dst = wh + gw * 1024;
        }
        dstp[tt] = dst;
#pragma unroll
        for (int i = 0; i < 8; i++) {
            int idx = i * 128 + tid;
            int rr = idx >> 5, cc = idx & 31;
            inT[tt * 1152 + cc * 36 + rr] = src[idx];
        }
    }
    __syncthreads();
    {
        const int tt = tid >> 6, l = tid & 63;
        const int n10 = (l >> 4) * 8;
        const int jj0 = (l & 15) * 4;
        float ac[8][4];
#pragma unroll
        for (int i = 0; i < 8; i++) { ac[i][0] = ac[i][1] = ac[i][2] = ac[i][3] = 0.f; }
#pragma unroll 4
        for (int k = 0; k < 32; k++) {
            float4 b  = *(const float4*)&T3c[k * 64 + jj0];
            float4 a0 = *(const float4*)&inT[tt * 1152 + k * 36 + n10];
            float4 a1 = *(const float4*)&inT[tt * 1152 + k * 36 + n10 + 4];
            fma4(ac[0], a0.x, b); fma4(ac[1], a0.y, b);
            fma4(ac[2], a0.z, b); fma4(ac[3], a0.w, b);
            fma4(ac[4], a1.x, b); fma4(ac[5], a1.y, b);
            fma4(ac[6], a1.z, b); fma4(ac[7], a1.w, b);
        }
#pragma unroll
        for (int i = 0; i < 8; i++)
            *(float4*)&G[tt * 2176 + (n10 + i) * 68 + jj0] =
                make_float4(ac[i][0], ac[i][1], ac[i][2], ac[i][3]);
    }
    __syncthreads();
    {
        const int tt = tid >> 6, l = tid & 63;
        const int k10 = (l >> 3) * 4;
        const int k20 = (l & 7) * 4;
        float ac[4][4];
#pragma unroll
        for (int i = 0; i < 4; i++) { ac[i][0] = ac[i][1] = ac[i][2] = ac[i][3] = 0.f; }
#pragma unroll 4
        for (int m = 0; m < 64; m++) {
            float4 av = *(const float4*)&T4c[m * 32 + k10];
            const int row = m & 31;
            const int col = (m < 32) ? k20 : (32 + k20);
            float4 bv = *(const float4*)&G[tt * 2176 + row * 68 + col];
            fma4(ac[0], av.x, bv); fma4(ac[1], av.y, bv);
            fma4(ac[2], av.z, bv); fma4(ac[3], av.w, bv);
        }
        float* dst = dstp[tt];
#pragma unroll
        for (int i = 0; i < 4; i++)
            *(float4*)&dst[(k10 + i) * 32 + k20] =
                make_float4(ac[i][0], ac[i][1], ac[i][2], ac[i][3]);
    }
}

// ---------------- Kernel B2: Y = DHT32(Ahat*What) per channel ----------------
__global__ __launch_bounds__(128) void kB2(float* ws, const float* __restrict__ wh) {
    __shared__ float prodT[2304];
    __shared__ float G[4352];
    __shared__ float T3c[2048];
    __shared__ float T4c[2048];
    const int tid = threadIdx.x;
    const int ch = blockIdx.x;
#pragma unroll
    for (int i = 0; i < 16; i++) {
        int t = i * 128 + tid;
        T3c[t] = ws[OFF_T3 + t];
        T4c[t] = ws[OFF_T4T + t];
    }
    float* xc = ws + OFF_XCY + ch * 2048;
    const float* whc = wh + ch * 2048;
#pragma unroll
    for (int i = 0; i < 16; i++) {
        int flat = i * 128 + tid;
        int c = flat >> 10, r = (flat >> 5) & 31, cc = flat & 31;
        prodT[c * 1152 + cc * 36 + r] = xc[flat] * whc[flat];
    }
    __syncthreads();
    {
        const int tt = tid >> 6, l = tid & 63;
        const int n10 = (l >> 4) * 8;
        const int jj0 = (l & 15) * 4;
        float ac[8][4];
#pragma unroll
        for (int i = 0; i < 8; i++) { ac[i][0] = ac[i][1] = ac[i][2] = ac[i][3] = 0.f; }
#pragma unroll 4
        for (int k = 0; k < 32; k++) {
            float4 b  = *(const float4*)&T3c[k * 64 + jj0];
            float4 a0 = *(const float4*)&prodT[tt * 1152 + k * 36 + n10];
            float4 a1 = *(const float4*)&prodT[tt * 1152 + k * 36 + n10 + 4];
            fma4(ac[0], a0.x, b); fma4(ac[1], a0.y, b);
            fma4(ac[2], a0.z, b); fma4(ac[3], a0.w, b);
            fma4(ac[4], a1.x, b); fma4(ac[5], a1.y, b);
            fma4(ac[6], a1.z, b); fma4(ac[7], a1.w, b);
        }
#pragma unroll
        for (int i = 0; i < 8; i++)
            *(float4*)&G[tt * 2176 + (n10 + i) * 68 + jj0] =
                make_float4(ac[i][0], ac[i][1], ac[i][2], ac[i][3]);
    }
    __syncthreads();
    {
        const int tt = tid >> 6, l = tid & 63;
        const int k10 = (l >> 3) * 4;
        const int k20 = (l & 7) * 4;
        float ac[4][4];
#pragma unroll
        for (int i = 0; i < 4; i++) { ac[i][0] = ac[i][1] = ac[i][2] = ac[i][3] = 0.f; }
#pragma unroll 4
        for (int m = 0; m < 64; m++) {
            float4 av = *(const float4*)&T4c[m * 32 + k10];
            const int row = m & 31;
            const int col = (m < 32) ? k20 : (32 + k20);
            float4 bv = *(const float4*)&G[tt * 2176 + row * 68 + col];
            fma4(ac[0], av.x, bv); fma4(ac[1], av.y, bv);
            fma4(ac[2], av.z, bv); fma4(ac[3], av.w, bv);
        }
        float* dst = xc + tt * 1024;
#pragma unroll
        for (int i = 0; i < 4; i++)
            *(float4*)&dst[(k10 + i) * 32 + k20] =
                make_float4(ac[i][0], ac[i][1], ac[i][2], ac[i][3]);
    }
}

// ---------------- Kernel C: Y -> out (per channel) ----------------
__global__ __launch_bounds__(256) void kC(float* __restrict__ out, const float* ws) {
    __shared__ float Yl[2304];
    __shared__ float TC[4352];
    __shared__ float UVt[8448];
    const int tid = threadIdx.x;
    const int ch = blockIdx.x;
    const float* yg = ws + OFF_XCY + ch * 2048;
#pragma unroll
    for (int i = 0; i < 8; i++) {
        int flat = i * 256 + tid;
        int j = flat >> 5, k2 = flat & 31;
        Yl[j * 36 + k2] = yg[flat];
    }
    for (int rc = 0; rc < 4; rc++) {
#pragma unroll
        for (int i = 0; i < 16; i++) {
            int flat = i * 256 + tid;
            int j = flat >> 6, rl = flat & 63;
            TC[j * 68 + rl] = ws[OFF_T5T + j * 256 + rc * 64 + rl];
        }
        __syncthreads();
        if (tid < 128) {
            const int rr0 = (tid >> 3) * 4;
            const int k20 = (tid & 7) * 4;
            float ac[4][4];
#pragma unroll
            for (int i = 0; i < 4; i++) { ac[i][0] = ac[i][1] = ac[i][2] = ac[i][3] = 0.f; }
#pragma unroll 4
            for (int j = 0; j < 64; j++) {
                float4 av = *(const float4*)&TC[j * 68 + rr0];
                float4 bv = *(const float4*)&Yl[j * 36 + k20];
                fma4(ac[0], av.x, bv); fma4(ac[1], av.y, bv);
                fma4(ac[2], av.z, bv); fma4(ac[3], av.w, bv);
            }
            const int msb = (rc < 2) ? k20 : (32 + k20);
            const int p = (rc * 64 + rr0) & 127;
#pragma unroll
            for (int ri = 0; ri < 4; ri++)
#pragma unroll
                for (int ki = 0; ki < 4; ki++)
                    UVt[(msb + ki) * 132 + p + ri] = ac[ri][ki];
        }
        __syncthreads();
    }
    for (int qh = 0; qh < 2; qh++) {
#pragma unroll
        for (int i = 0; i < 16; i++) {
            int flat = i * 256 + tid;
            int m = flat >> 6, ql = flat & 63;
            TC[m * 68 + ql] = ws[OFF_T6 + m * 128 + qh * 64 + ql];
        }
        __syncthreads();
        const int p0 = (tid >> 4) * 8;
        const int q0 = (tid & 15) * 4;
        float ac[8][4];
#pragma unroll
        for (int i = 0; i < 8; i++) { ac[i][0] = ac[i][1] = ac[i][2] = ac[i][3] = 0.f; }
#pragma unroll 4
        for (int m = 0; m < 64; m++) {
            float4 b  = *(const float4*)&TC[m * 68 + q0];
            float4 a0 = *(const float4*)&UVt[m * 132 + p0];
            float4 a1 = *(const float4*)&UVt[m * 132 + p0 + 4];
            fma4(ac[0], a0.x, b); fma4(ac[1], a0.y, b);
            fma4(ac[2], a0.z, b); fma4(ac[3], a0.w, b);
            fma4(ac[4], a1.x, b); fma4(ac[5], a1.y, b);
            fma4(ac[6], a1.z, b); fma4(ac[7], a1.w, b);
        }
#pragma unroll
        for (int i = 0; i < 8; i++)
            *(float4*)&out[ch * 16384 + (p0 + i) * 128 + qh * 64 + q0] =
                make_float4(ac[i][0], ac[i][1], ac[i][2], ac[i][3]);
        __syncthreads();
    }
}

extern "C" void kernel_launch(void* const* d_in, const int* in_sizes, int n_in,
                              void* d_out, int out_size, void* d_ws, size_t ws_size,
                              hipStream_t stream) {
    (void)in_sizes; (void)n_in; (void)out_size;
    if (ws_size < (size_t)WS_FLOATS * sizeof(float)) return;  // need ~33.8 MB scratch
    const float* x  = (const float*)d_in[0];
    const float* w1 = (const float*)d_in[1];
    const float* w2 = (const float*)d_in[2];
    float* out = (float*)d_out;
    float* ws  = (float*)d_ws;
    float* wh  = out;  // What scratch lives in d_out (first 33.5 MB), overwritten by kC later
    unsigned short* tf = (unsigned short*)((char*)d_out + TF_BYTE_OFF);  // frag tables @ +64MB

    hipLaunchKernelGGL(init_tables, dim3(208), dim3(256), 0, stream, ws);
    hipLaunchKernelGGL(init_frag, dim3(192), dim3(256), 0, stream, tf);
    hipLaunchKernelGGL(kA,  dim3(4096), dim3(256), 0, stream, x, ws, tf);
    hipLaunchKernelGGL(kB1, dim3(8192), dim3(128), 0, stream, w1, w2, ws, wh);
    hipLaunchKernelGGL(kB2, dim3(4096), dim3(128), 0, stream, ws, wh);
    hipLaunchKernelGGL(kC,  dim3(4096), dim3(256), 0, stream, out, ws);
}

// Round 3
// 635.581 us; speedup vs baseline: 1.3642x; 1.1894x over previous
//
#include <hip/hip_runtime.h>

// SpectralConv2d DHT pipeline, B=CIN=COUT=64, H=W=128, M1=M2=32.
// Everything is per flat channel ch in [0,4096): pure elementwise in ch.
//
// Pipeline per channel (all scales folded into tables):
//   A : CS[n1][j] = x(128x128) . T1(128x64)         [MFMA split-bf16]
//       Xc[i][k2] = T2t^T(64x256) . stack(CS)       [MFMA split-bf16]
//   B1: hat = T4t^T . stack(tile . T3)              (DHT32 of Xc crops and of w1/w2 tiles)
//   B2: Y = T4t^T . stack((Ahat*What) . T3)
//   C : UVT(32x256) = Yt(32x64) . T5(64x256)        [MFMA split-bf16]
//       out(128x128) = WT(128x64) . T6(64x128)      [MFMA split-bf16, s4 folded in T6]
//
// ws layout (floats): [0,2048) T3, [2048,4096) T4t,
//   [4096,53248) frag tables (as ushort: 98304 = T1f 16384 | T2f 32768 | T5f 32768 | T6f 16384),
//   [53248,...) XCY per-channel scratch. WS_FLOATS unchanged vs prior round.

#define OFF_T3   0        // [32][64]
#define OFF_T4T  2048     // [64][32]
#define OFF_TF   4096     // frag tables, 98304 ushorts
#define OFF_XCY  53248    // [4096][64][32] (Xc, then Y in place)
#define WS_FLOATS (53248 + 4096 * 2048)

typedef __attribute__((ext_vector_type(8))) short bf16x8;
typedef __attribute__((ext_vector_type(4))) float f32x4;

__device__ __forceinline__ int kmap(int i) { return (i < 32) ? i : 64 + i; }

__device__ __forceinline__ unsigned short f2bf(float f) {
    unsigned int u = __float_as_uint(f);
    return (unsigned short)((u + 0x7fffu + ((u >> 16) & 1u)) >> 16);  // RNE
}
__device__ __forceinline__ float bf2f(unsigned short h) {
    return __uint_as_float(((unsigned int)h) << 16);
}

__device__ __forceinline__ void fma4(float* a, float s, float4 b) {
    a[0] = fmaf(s, b.x, a[0]); a[1] = fmaf(s, b.y, a[1]);
    a[2] = fmaf(s, b.z, a[2]); a[3] = fmaf(s, b.w, a[3]);
}

__global__ __launch_bounds__(256) void init_tables(float* ws) {
    int idx = blockIdx.x * 256 + threadIdx.x;
    if (idx >= 4096) return;
    const float w32 = 6.2831853071795864769f / 32.0f;
    if (idx < 2048) {                       // T3[n2][j]: j<32 cos(2pi j n2/32) else sin
        int n2 = idx >> 6, j = idx & 63, jj = j & 31;
        float a = w32 * (float)((jj * n2) & 31);
        ws[OFF_T3 + idx] = (j < 32) ? cosf(a) : sinf(a);
    } else {                                // T4t[m][k1]: m<32 cas(+k1 m), else cas(-k1(m-32)); /1024
        int t = idx - 2048, m = t >> 5, k1 = t & 31;
        float v;
        if (m < 32) { float a = w32 * (float)((k1 * m) & 31); v = cosf(a) + sinf(a); }
        else { int mm = m - 32; float a = w32 * (float)((k1 * mm) & 31); v = cosf(a) - sinf(a); }
        ws[OFF_T4T + t] = v * (1.0f / 1024.0f);
    }
}

// Fragment-linear bf16 hi/lo tables (MFMA 16x16x32 layouts):
//   A[l%16][8*(l/16)+i], B[8*(l/16)+i][l%16].
__global__ __launch_bounds__(256) void init_frag(float* ws) {
    unsigned short* tf = (unsigned short*)(ws + OFF_TF);
    int idx = blockIdx.x * 256 + threadIdx.x;
    if (idx >= 98304) return;
    const float w128 = 6.2831853071795864769f / 128.0f;
    float v;
    int hl;
    if (idx < 16384) {
        // T1frag: frag=((ks*4+nt)*2+hl); B[k][n]=T1[n2=ks*32+8*(l/16)+i][j=nt*16+l%16]
        int frag = idx >> 9, lane = (idx >> 3) & 63, ii = idx & 7;
        hl = frag & 1;
        int nt = (frag >> 1) & 3, ks = frag >> 3;
        int n2 = ks * 32 + (lane >> 4) * 8 + ii;
        int j = nt * 16 + (lane & 15);
        int jj = j & 31;
        float a = w128 * (float)((jj * n2) & 127);
        v = (j < 32) ? cosf(a) : sinf(a);
    } else if (idx < 49152) {
        // T2frag: frag=((mt*8+ks)*2+hl); A[io][m]=T2t[m=ks*32+8*(l/16)+i][io=mt*16+l%16]
        int t = idx - 16384;
        int frag = t >> 9, lane = (t >> 3) & 63, ii = t & 7;
        hl = frag & 1;
        int ks = (frag >> 1) & 7, mt = frag >> 4;
        int m = ks * 32 + (lane >> 4) * 8 + ii;
        int io = mt * 16 + (lane & 15);
        int k1 = kmap(io);
        if (m < 128) { float a = w128 * (float)((k1 * m) & 127); v = cosf(a) + sinf(a); }
        else { int mm = m - 128; float a = w128 * (float)((k1 * mm) & 127); v = cosf(a) - sinf(a); }
        v *= (1.0f / 16384.0f);
    } else if (idx < 81920) {
        // T5frag: frag=((ks*16+nt)*2+hl); B[k][n]=T5t[j=ks*32+8*(l/16)+i][r=nt*16+l%16]
        int t = idx - 49152;
        int frag = t >> 9, lane = (t >> 3) & 63, ii = t & 7;
        hl = frag & 1;
        int nt = (frag >> 1) & 15, ks = frag >> 5;
        int j = ks * 32 + (lane >> 4) * 8 + ii;
        int r = nt * 16 + (lane & 15);
        int k1 = kmap(j);
        int p = r & 127;
        float a = w128 * (float)((p * k1) & 127);
        v = (r < 128) ? cosf(a) : sinf(a);
    } else {
        // T6frag: frag=((ks*8+nt)*2+hl); B[k][n]=T6[ms=ks*32+8*(l/16)+i][q=nt*16+l%16]
        int t = idx - 81920;
        int frag = t >> 9, lane = (t >> 3) & 63, ii = t & 7;
        hl = frag & 1;
        int nt = (frag >> 1) & 7, ks = frag >> 4;
        int ms = ks * 32 + (lane >> 4) * 8 + ii;
        int q = nt * 16 + (lane & 15);
        int k2 = ms & 31;
        float a = w128 * (float)((q * k2) & 127);
        float c = cosf(a), s = sinf(a);
        const float s4 = 1.0f / 67108864.0f;  // (1/64)*(1/16384)*(1/64)
        v = ((ms < 32) ? (c + s) : (c - s)) * s4;
    }
    unsigned short h = f2bf(v);
    tf[idx] = hl ? f2bf(v - bf2f(h)) : h;
}

// ---------------- Kernel A: x -> Xc (per channel), MFMA split-bf16 ----------------
__global__ __launch_bounds__(256) void kA(const float* __restrict__ x, float* ws) {
    __shared__ unsigned short CSThi[64 * 136];  // CST[j][n1], pitch 136 (272B rows, 16B-aligned)
    __shared__ unsigned short CSTlo[64 * 136];
    const int tid  = threadIdx.x;
    const int lane = tid & 63;
    const int wv   = tid >> 6;           // 4 waves
    const int ch   = blockIdx.x;
    const float* xg = x + ch * 16384;
    const int lr = lane & 15;
    const int lk = (lane >> 4) * 8;
    const int lq = (lane >> 4) * 4;

    const unsigned short* tf = (const unsigned short*)(ws + OFF_TF);
    const bf16x8* t1f = (const bf16x8*)tf;            // 32 frags
    const bf16x8* t2f = (const bf16x8*)tf + 32 * 64;  // 64 frags

    const f32x4 zero4 = {0.f, 0.f, 0.f, 0.f};

    // phase 1: CS = x(128x128) . T1(128x64).  Wave wv owns rows [wv*32, wv*32+32).
    f32x4 acc[2][4];
#pragma unroll
    for (int mt = 0; mt < 2; mt++)
#pragma unroll
        for (int nt = 0; nt < 4; nt++) acc[mt][nt] = zero4;

#pragma unroll
    for (int ks = 0; ks < 4; ks++) {
        bf16x8 ah[2], al[2];
#pragma unroll
        for (int mt = 0; mt < 2; mt++) {
            const float* src = xg + (wv * 32 + mt * 16 + lr) * 128 + ks * 32 + lk;
            float4 u0 = *(const float4*)src;
            float4 u1 = *(const float4*)(src + 4);
            float av[8] = {u0.x, u0.y, u0.z, u0.w, u1.x, u1.y, u1.z, u1.w};
#pragma unroll
            for (int i = 0; i < 8; i++) {
                unsigned short h = f2bf(av[i]);
                ah[mt][i] = (short)h;
                al[mt][i] = (short)f2bf(av[i] - bf2f(h));
            }
        }
#pragma unroll
        for (int nt = 0; nt < 4; nt++) {
            bf16x8 bh = t1f[((ks * 4 + nt) * 2 + 0) * 64 + lane];
            bf16x8 bl = t1f[((ks * 4 + nt) * 2 + 1) * 64 + lane];
#pragma unroll
            for (int mt = 0; mt < 2; mt++) {
                acc[mt][nt] = __builtin_amdgcn_mfma_f32_16x16x32_bf16(ah[mt], bh, acc[mt][nt], 0, 0, 0);
                acc[mt][nt] = __builtin_amdgcn_mfma_f32_16x16x32_bf16(ah[mt], bl, acc[mt][nt], 0, 0, 0);
                acc[mt][nt] = __builtin_amdgcn_mfma_f32_16x16x32_bf16(al[mt], bh, acc[mt][nt], 0, 0, 0);
            }
        }
    }

    // CS -> CST (transposed) in LDS as bf16 hi/lo.
#pragma unroll
    for (int mt = 0; mt < 2; mt++)
#pragma unroll
        for (int nt = 0; nt < 4; nt++) {
            const int j  = nt * 16 + lr;
            const int n1 = wv * 32 + mt * 16 + lq;
            unsigned short h[4], lo[4];
#pragma unroll
            for (int r = 0; r < 4; r++) {
                float v = acc[mt][nt][r];
                h[r]  = f2bf(v);
                lo[r] = f2bf(v - bf2f(h[r]));
            }
            uint2 hv = make_uint2((unsigned int)h[0] | ((unsigned int)h[1] << 16),
                                  (unsigned int)h[2] | ((unsigned int)h[3] << 16));
            uint2 lv = make_uint2((unsigned int)lo[0] | ((unsigned int)lo[1] << 16),
                                  (unsigned int)lo[2] | ((unsigned int)lo[3] << 16));
            *(uint2*)&CSThi[j * 136 + n1] = hv;
            *(uint2*)&CSTlo[j * 136 + n1] = lv;
        }
    __syncthreads();

    // phase 2: Xc = A(64x256) . CSbig(256x32); CSbig[m][k2] = CST[k2 + 32*(m>=128)][m%128].
    f32x4 a2[2] = {zero4, zero4};
#pragma unroll
    for (int ks = 0; ks < 8; ks++) {
        bf16x8 ah = t2f[((wv * 8 + ks) * 2 + 0) * 64 + lane];
        bf16x8 al = t2f[((wv * 8 + ks) * 2 + 1) * 64 + lane];
        const int colb = (ks & 3) * 32 + lk;
        const int rofs = (ks >= 4) ? 32 : 0;
#pragma unroll
        for (int nt = 0; nt < 2; nt++) {
            const int row = nt * 16 + lr + rofs;
            bf16x8 bh = *(const bf16x8*)&CSThi[row * 136 + colb];
            bf16x8 bl = *(const bf16x8*)&CSTlo[row * 136 + colb];
            a2[nt] = __builtin_amdgcn_mfma_f32_16x16x32_bf16(ah, bh, a2[nt], 0, 0, 0);
            a2[nt] = __builtin_amdgcn_mfma_f32_16x16x32_bf16(ah, bl, a2[nt], 0, 0, 0);
            a2[nt] = __builtin_amdgcn_mfma_f32_16x16x32_bf16(al, bh, a2[nt], 0, 0, 0);
        }
    }
    float* xcg = ws + OFF_XCY + ch * 2048;
#pragma unroll
    for (int nt = 0; nt < 2; nt++)
#pragma unroll
        for (int r = 0; r < 4; r++) {
            const int io = wv * 16 + lq + r;
            xcg[io * 32 + nt * 16 + lr] = a2[nt][r];
        }
}

// ---------------- Kernel B1: DHT32 of all Xc crops and w tiles ----------------
__global__ __launch_bounds__(128) void kB1(const float* __restrict__ w1, const float* __restrict__ w2,
                                           float* ws, float* wh) {
    __shared__ float inT[2304];  // [2][32][36]
    __shared__ float G[4352];    // [2][32][68]
    __shared__ float T3c[2048];
    __shared__ float T4c[2048];
    const int tid = threadIdx.x;
#pragma unroll
    for (int i = 0; i < 16; i++) {
        int t = i * 128 + tid;
        T3c[t] = ws[OFF_T3 + t];
        T4c[t] = ws[OFF_T4T + t];
    }
    float* dstp[2];
#pragma unroll
    for (int tt = 0; tt < 2; tt++) {
        int g = blockIdx.x * 2 + tt;
        const float* src; float* dst;
        if (g < 8192) {
            int ch = g >> 1, crop = g & 1;
            dst = ws + OFF_XCY + ch * 2048 + crop * 1024;
            src = dst;
        } else {
            int gw = g - 8192;
            int ch = gw >> 1, t2 = gw & 1;
            src = (t2 ? w2 : w1) + ch * 1024;
            dst = wh + gw * 1024;
        }
        dstp[tt] = dst;
#pragma unroll
        for (int i = 0; i < 8; i++) {
            int idx = i * 128 + tid;
            int rr = idx >> 5, cc = idx & 31;
            inT[tt * 1152 + cc * 36 + rr] = src[idx];
        }
    }
    __syncthreads();
    {
        const int tt = tid >> 6, l = tid & 63;
        const int n10 = (l >> 4) * 8;
        const int jj0 = (l & 15) * 4;
        float ac[8][4];
#pragma unroll
        for (int i = 0; i < 8; i++) { ac[i][0] = ac[i][1] = ac[i][2] = ac[i][3] = 0.f; }
#pragma unroll 4
        for (int k = 0; k < 32; k++) {
            float4 b  = *(const float4*)&T3c[k * 64 + jj0];
            float4 a0 = *(const float4*)&inT[tt * 1152 + k * 36 + n10];
            float4 a1 = *(const float4*)&inT[tt * 1152 + k * 36 + n10 + 4];
            fma4(ac[0], a0.x, b); fma4(ac[1], a0.y, b);
            fma4(ac[2], a0.z, b); fma4(ac[3], a0.w, b);
            fma4(ac[4], a1.x, b); fma4(ac[5], a1.y, b);
            fma4(ac[6], a1.z, b); fma4(ac[7], a1.w, b);
        }
#pragma unroll
        for (int i = 0; i < 8; i++)
            *(float4*)&G[tt * 2176 + (n10 + i) * 68 + jj0] =
                make_float4(ac[i][0], ac[i][1], ac[i][2], ac[i][3]);
    }
    __syncthreads();
    {
        const int tt = tid >> 6, l = tid & 63;
        const int k10 = (l >> 3) * 4;
        const int k20 = (l & 7) * 4;
        float ac[4][4];
#pragma unroll
        for (int i = 0; i < 4; i++) { ac[i][0] = ac[i][1] = ac[i][2] = ac[i][3] = 0.f; }
#pragma unroll 4
        for (int m = 0; m < 64; m++) {
            float4 av = *(const float4*)&T4c[m * 32 + k10];
            const int row = m & 31;
            const int col = (m < 32) ? k20 : (32 + k20);
            float4 bv = *(const float4*)&G[tt * 2176 + row * 68 + col];
            fma4(ac[0], av.x, bv); fma4(ac[1], av.y, bv);
            fma4(ac[2], av.z, bv); fma4(ac[3], av.w, bv);
        }
        float* dst = dstp[tt];
#pragma unroll
        for (int i = 0; i < 4; i++)
            *(float4*)&dst[(k10 + i) * 32 + k20] =
                make_float4(ac[i][0], ac[i][1], ac[i][2], ac[i][3]);
    }
}

// ---------------- Kernel B2: Y = DHT32(Ahat*What) per channel ----------------
__global__ __launch_bounds__(128) void kB2(float* ws, const float* __restrict__ wh) {
    __shared__ float prodT[2304];
    __shared__ float G[4352];
    __shared__ float T3c[2048];
    __shared__ float T4c[2048];
    const int tid = threadIdx.x;
    const int ch = blockIdx.x;
#pragma unroll
    for (int i = 0; i < 16; i++) {
        int t = i * 128 + tid;
        T3c[t] = ws[OFF_T3 + t];
        T4c[t] = ws[OFF_T4T + t];
    }
    float* xc = ws + OFF_XCY + ch * 2048;
    const float* whc = wh + ch * 2048;
#pragma unroll
    for (int i = 0; i < 16; i++) {
        int flat = i * 128 + tid;
        int c = flat >> 10, r = (flat >> 5) & 31, cc = flat & 31;
        prodT[c * 1152 + cc * 36 + r] = xc[flat] * whc[flat];
    }
    __syncthreads();
    {
        const int tt = tid >> 6, l = tid & 63;
        const int n10 = (l >> 4) * 8;
        const int jj0 = (l & 15) * 4;
        float ac[8][4];
#pragma unroll
        for (int i = 0; i < 8; i++) { ac[i][0] = ac[i][1] = ac[i][2] = ac[i][3] = 0.f; }
#pragma unroll 4
        for (int k = 0; k < 32; k++) {
            float4 b  = *(const float4*)&T3c[k * 64 + jj0];
            float4 a0 = *(const float4*)&prodT[tt * 1152 + k * 36 + n10];
            float4 a1 = *(const float4*)&prodT[tt * 1152 + k * 36 + n10 + 4];
            fma4(ac[0], a0.x, b); fma4(ac[1], a0.y, b);
            fma4(ac[2], a0.z, b); fma4(ac[3], a0.w, b);
            fma4(ac[4], a1.x, b); fma4(ac[5], a1.y, b);
            fma4(ac[6], a1.z, b); fma4(ac[7], a1.w, b);
        }
#pragma unroll
        for (int i = 0; i < 8; i++)
            *(float4*)&G[tt * 2176 + (n10 + i) * 68 + jj0] =
                make_float4(ac[i][0], ac[i][1], ac[i][2], ac[i][3]);
    }
    __syncthreads();
    {
        const int tt = tid >> 6, l = tid & 63;
        const int k10 = (l >> 3) * 4;
        const int k20 = (l & 7) * 4;
        float ac[4][4];
#pragma unroll
        for (int i = 0; i < 4; i++) { ac[i][0] = ac[i][1] = ac[i][2] = ac[i][3] = 0.f; }
#pragma unroll 4
        for (int m = 0; m < 64; m++) {
            float4 av = *(const float4*)&T4c[m * 32 + k10];
            const int row = m & 31;
            const int col = (m < 32) ? k20 : (32 + k20);
            float4 bv = *(const float4*)&G[tt * 2176 + row * 68 + col];
            fma4(ac[0], av.x, bv); fma4(ac[1], av.y, bv);
            fma4(ac[2], av.z, bv); fma4(ac[3], av.w, bv);
        }
        float* dst = xc + tt * 1024;
#pragma unroll
        for (int i = 0; i < 4; i++)
            *(float4*)&dst[(k10 + i) * 32 + k20] =
                make_float4(ac[i][0], ac[i][1], ac[i][2], ac[i][3]);
    }
}

// ---------------- Kernel C: Y -> out (per channel), MFMA split-bf16 ----------------
// GEMM1 (transposed): UVT(32x256) = Yt(32x64) . T5(64x256); A = Yt from LDS, B = T5frag.
// Intermediate: WT[p][ms] = UV-derived, bf16 hi/lo, pitch 72 (144B rows, 16B-aligned).
// GEMM2: out(128x128) = WT(128x64) . T6(64x128); A = WT from LDS, B = T6frag.
__global__ __launch_bounds__(256) void kC(float* __restrict__ out, float* ws) {
    __shared__ unsigned short YThi[32 * 72];   // YT[k2][j], pitch 72
    __shared__ unsigned short YTlo[32 * 72];
    __shared__ unsigned short WThi[128 * 72];  // WT[p][ms], pitch 72
    __shared__ unsigned short WTlo[128 * 72];
    const int tid  = threadIdx.x;
    const int lane = tid & 63;
    const int wv   = tid >> 6;           // 4 waves
    const int ch   = blockIdx.x;
    const int lr = lane & 15;
    const int lk = (lane >> 4) * 8;
    const int lq = (lane >> 4) * 4;
    const float* yg = ws + OFF_XCY + ch * 2048;

    const unsigned short* tf = (const unsigned short*)(ws + OFF_TF);
    const bf16x8* t5f = (const bf16x8*)tf + 6144;   // 64 frags: ((ks*16+nt)*2+hl)
    const bf16x8* t6f = (const bf16x8*)tf + 10240;  // 32 frags: ((ks*8+nt)*2+hl)

    const f32x4 zero4 = {0.f, 0.f, 0.f, 0.f};

    // stage Y (64x32 f32) -> YT[k2][j] bf16 hi/lo (transposed)
    {
        const int base = tid * 8;                 // j = base>>5, k2 = base&31 .. +7
        const int j = base >> 5, k2b = base & 31;
        float4 u0 = *(const float4*)&yg[base];
        float4 u1 = *(const float4*)&yg[base + 4];
        float av[8] = {u0.x, u0.y, u0.z, u0.w, u1.x, u1.y, u1.z, u1.w};
#pragma unroll
        for (int i = 0; i < 8; i++) {
            unsigned short h = f2bf(av[i]);
            YThi[(k2b + i) * 72 + j] = h;
            YTlo[(k2b + i) * 72 + j] = f2bf(av[i] - bf2f(h));
        }
    }
    __syncthreads();

    // GEMM1: UVT[k2][r] = sum_j Yt[k2][j] * T5t[j][r].  Wave wv: nt = wv*4..wv*4+3.
    f32x4 acc1[2][4];
#pragma unroll
    for (int mt = 0; mt < 2; mt++)
#pragma unroll
        for (int n = 0; n < 4; n++) acc1[mt][n] = zero4;
    bf16x8 yh[2][2], yl[2][2];
#pragma unroll
    for (int mt = 0; mt < 2; mt++)
#pragma unroll
        for (int ks = 0; ks < 2; ks++) {
            yh[mt][ks] = *(const bf16x8*)&YThi[(mt * 16 + lr) * 72 + ks * 32 + lk];
            yl[mt][ks] = *(const bf16x8*)&YTlo[(mt * 16 + lr) * 72 + ks * 32 + lk];
        }
#pragma unroll
    for (int ks = 0; ks < 2; ks++)
#pragma unroll
        for (int ntl = 0; ntl < 4; ntl++) {
            const int nt = wv * 4 + ntl;
            bf16x8 bh = t5f[((ks * 16 + nt) * 2 + 0) * 64 + lane];
            bf16x8 bl = t5f[((ks * 16 + nt) * 2 + 1) * 64 + lane];
#pragma unroll
            for (int mt = 0; mt < 2; mt++) {
                acc1[mt][ntl] = __builtin_amdgcn_mfma_f32_16x16x32_bf16(yh[mt][ks], bh, acc1[mt][ntl], 0, 0, 0);
                acc1[mt][ntl] = __builtin_amdgcn_mfma_f32_16x16x32_bf16(yh[mt][ks], bl, acc1[mt][ntl], 0, 0, 0);
                acc1[mt][ntl] = __builtin_amdgcn_mfma_f32_16x16x32_bf16(yl[mt][ks], bh, acc1[mt][ntl], 0, 0, 0);
            }
        }

    // UVT -> WT: value at (k2 = mt*16+lq+rr, r = nt*16+lr); p = r%128, ms = k2 + 32*(r>=128).
    // 4 consecutive rr = 4 consecutive ms -> packed uint2 writes.
#pragma unroll
    for (int mt = 0; mt < 2; mt++)
#pragma unroll
        for (int ntl = 0; ntl < 4; ntl++) {
            const int nt = wv * 4 + ntl;
            const int p = (nt & 7) * 16 + lr;
            const int ms0 = ((nt >= 8) ? 32 : 0) + mt * 16 + lq;
            unsigned short h[4], lo[4];
#pragma unroll
            for (int r = 0; r < 4; r++) {
                float v = acc1[mt][ntl][r];
                h[r]  = f2bf(v);
                lo[r] = f2bf(v - bf2f(h[r]));
            }
            *(uint2*)&WThi[p * 72 + ms0] =
                make_uint2((unsigned int)h[0] | ((unsigned int)h[1] << 16),
                           (unsigned int)h[2] | ((unsigned int)h[3] << 16));
            *(uint2*)&WTlo[p * 72 + ms0] =
                make_uint2((unsigned int)lo[0] | ((unsigned int)lo[1] << 16),
                           (unsigned int)lo[2] | ((unsigned int)lo[3] << 16));
        }
    __syncthreads();

    // GEMM2: out[p][q] = sum_ms WT[p][ms] * T6[ms][q].  Wave wv: mt = wv*2, wv*2+1.
    bf16x8 wth[2][2], wtl[2][2];
#pragma unroll
    for (int mtl = 0; mtl < 2; mtl++)
#pragma unroll
        for (int ks = 0; ks < 2; ks++) {
            const int row = (wv * 2 + mtl) * 16 + lr;
            wth[mtl][ks] = *(const bf16x8*)&WThi[row * 72 + ks * 32 + lk];
            wtl[mtl][ks] = *(const bf16x8*)&WTlo[row * 72 + ks * 32 + lk];
        }
    f32x4 acc2[2][8];
#pragma unroll
    for (int mtl = 0; mtl < 2; mtl++)
#pragma unroll
        for (int n = 0; n < 8; n++) acc2[mtl][n] = zero4;
#pragma unroll
    for (int ks = 0; ks < 2; ks++)
#pragma unroll
        for (int nt = 0; nt < 8; nt++) {
            bf16x8 bh = t6f[((ks * 8 + nt) * 2 + 0) * 64 + lane];
            bf16x8 bl = t6f[((ks * 8 + nt) * 2 + 1) * 64 + lane];
#pragma unroll
            for (int mtl = 0; mtl < 2; mtl++) {
                acc2[mtl][nt] = __builtin_amdgcn_mfma_f32_16x16x32_bf16(wth[mtl][ks], bh, acc2[mtl][nt], 0, 0, 0);
                acc2[mtl][nt] = __builtin_amdgcn_mfma_f32_16x16x32_bf16(wth[mtl][ks], bl, acc2[mtl][nt], 0, 0, 0);
                acc2[mtl][nt] = __builtin_amdgcn_mfma_f32_16x16x32_bf16(wtl[mtl][ks], bh, acc2[mtl][nt], 0, 0, 0);
            }
        }
    float* og = out + ch * 16384;
#pragma unroll
    for (int mtl = 0; mtl < 2; mtl++) {
        const int pb = (wv * 2 + mtl) * 16 + lq;
#pragma unroll
        for (int nt = 0; nt < 8; nt++)
#pragma unroll
            for (int r = 0; r < 4; r++)
                og[(pb + r) * 128 + nt * 16 + lr] = acc2[mtl][nt][r];
    }
}

extern "C" void kernel_launch(void* const* d_in, const int* in_sizes, int n_in,
                              void* d_out, int out_size, void* d_ws, size_t ws_size,
                              hipStream_t stream) {
    (void)in_sizes; (void)n_in; (void)out_size;
    if (ws_size < (size_t)WS_FLOATS * sizeof(float)) return;  // need ~33.8 MB scratch
    const float* x  = (const float*)d_in[0];
    const float* w1 = (const float*)d_in[1];
    const float* w2 = (const float*)d_in[2];
    float* out = (float*)d_out;
    float* ws  = (float*)d_ws;
    float* wh  = out;  // What scratch in d_out, consumed by kB2 before kC overwrites

    hipLaunchKernelGGL(init_tables, dim3(16), dim3(256), 0, stream, ws);
    hipLaunchKernelGGL(init_frag, dim3(384), dim3(256), 0, stream, ws);
    hipLaunchKernelGGL(kA,  dim3(4096), dim3(256), 0, stream, x, ws);
    hipLaunchKernelGGL(kB1, dim3(8192), dim3(128), 0, stream, w1, w2, ws, wh);
    hipLaunchKernelGGL(kB2, dim3(4096), dim3(128), 0, stream, ws, wh);
    hipLaunchKernelGGL(kC,  dim3(4096), dim3(256), 0, stream, out, ws);
}

// Round 4
// 557.310 us; speedup vs baseline: 1.5558x; 1.1404x over previous
//
#include <hip/hip_runtime.h>

// SpectralConv2d DHT pipeline, B=CIN=COUT=64, H=W=128, M1=M2=32.
// FULLY FUSED: the whole pipeline is elementwise in flat channel ch in [0,4096),
// so one block computes one channel end-to-end with zero global intermediates.
//
// Per channel (all scales folded into tables, all GEMMs MFMA split-bf16):
//   A1: CS[n1][j] = x(128x128) . T1(128x64)
//   A2: Xc[i][k2] = T2t^T(64x256) . stack(CS)     (crop0 = rows 0..31, crop1 = 32..63)
//   B1: hat_t = T4t^T . stack(tile_t . T3)        (4 tiles: crop0, crop1, w1, w2)
//   B2: Y_t  = T4t^T . stack((hatX_t*hatW_t) . T3)
//   C1: UVT(32x256) = Yt(32x64) . T5(64x256)
//   C2: out(128x128) = WT(128x64) . T6(64x128)    (s4 folded in T6)
//
// ws layout: frag tables only, 106496 ushorts:
//   T1f 16384 | T2f 32768 | T5f 32768 | T6f 16384 | T3f 4096 | T4f 4096

#define WS_FLOATS 53248

typedef __attribute__((ext_vector_type(8))) short bf16x8;
typedef __attribute__((ext_vector_type(4))) float f32x4;

__device__ __forceinline__ int kmap(int i) { return (i < 32) ? i : 64 + i; }

__device__ __forceinline__ unsigned short f2bf(float f) {
    unsigned int u = __float_as_uint(f);
    return (unsigned short)((u + 0x7fffu + ((u >> 16) & 1u)) >> 16);  // RNE
}
__device__ __forceinline__ float bf2f(unsigned short h) {
    return __uint_as_float(((unsigned int)h) << 16);
}

__device__ __forceinline__ void pack4(f32x4 v, uint2* hv, uint2* lv) {
    unsigned short h[4], lo[4];
#pragma unroll
    for (int r = 0; r < 4; r++) {
        h[r]  = f2bf(v[r]);
        lo[r] = f2bf(v[r] - bf2f(h[r]));
    }
    *hv = make_uint2((unsigned int)h[0] | ((unsigned int)h[1] << 16),
                     (unsigned int)h[2] | ((unsigned int)h[3] << 16));
    *lv = make_uint2((unsigned int)lo[0] | ((unsigned int)lo[1] << 16),
                     (unsigned int)lo[2] | ((unsigned int)lo[3] << 16));
}

// Fragment-linear bf16 hi/lo tables (MFMA 16x16x32 layouts):
//   A[l%16][8*(l/16)+i], B[8*(l/16)+i][l%16].
__global__ __launch_bounds__(256) void init_frag(float* ws) {
    unsigned short* tf = (unsigned short*)ws;
    int idx = blockIdx.x * 256 + threadIdx.x;
    if (idx >= 106496) return;
    const float w128 = 6.2831853071795864769f / 128.0f;
    const float w32  = 6.2831853071795864769f / 32.0f;
    float v;
    int hl;
    if (idx < 16384) {
        // T1f: frag=((ks*4+nt)*2+hl); B[k][n]=T1[n2=ks*32+8*(l/16)+i][j=nt*16+l%16]
        int frag = idx >> 9, lane = (idx >> 3) & 63, ii = idx & 7;
        hl = frag & 1;
        int nt = (frag >> 1) & 3, ks = frag >> 3;
        int n2 = ks * 32 + (lane >> 4) * 8 + ii;
        int j = nt * 16 + (lane & 15);
        int jj = j & 31;
        float a = w128 * (float)((jj * n2) & 127);
        v = (j < 32) ? cosf(a) : sinf(a);
    } else if (idx < 49152) {
        // T2f: frag=((mt*8+ks)*2+hl); A[io][m]=T2t[m=ks*32+8*(l/16)+i][io=mt*16+l%16]
        int t = idx - 16384;
        int frag = t >> 9, lane = (t >> 3) & 63, ii = t & 7;
        hl = frag & 1;
        int ks = (frag >> 1) & 7, mt = frag >> 4;
        int m = ks * 32 + (lane >> 4) * 8 + ii;
        int io = mt * 16 + (lane & 15);
        int k1 = kmap(io);
        if (m < 128) { float a = w128 * (float)((k1 * m) & 127); v = cosf(a) + sinf(a); }
        else { int mm = m - 128; float a = w128 * (float)((k1 * mm) & 127); v = cosf(a) - sinf(a); }
        v *= (1.0f / 16384.0f);
    } else if (idx < 81920) {
        // T5f: frag=((ks*16+nt)*2+hl); B[k][n]=T5t[j=ks*32+8*(l/16)+i][r=nt*16+l%16]
        int t = idx - 49152;
        int frag = t >> 9, lane = (t >> 3) & 63, ii = t & 7;
        hl = frag & 1;
        int nt = (frag >> 1) & 15, ks = frag >> 5;
        int j = ks * 32 + (lane >> 4) * 8 + ii;
        int r = nt * 16 + (lane & 15);
        int k1 = kmap(j);
        int p = r & 127;
        float a = w128 * (float)((p * k1) & 127);
        v = (r < 128) ? cosf(a) : sinf(a);
    } else if (idx < 98304) {
        // T6f: frag=((ks*8+nt)*2+hl); B[k][n]=T6[ms=ks*32+8*(l/16)+i][q=nt*16+l%16]
        int t = idx - 81920;
        int frag = t >> 9, lane = (t >> 3) & 63, ii = t & 7;
        hl = frag & 1;
        int nt = (frag >> 1) & 7, ks = frag >> 4;
        int ms = ks * 32 + (lane >> 4) * 8 + ii;
        int q = nt * 16 + (lane & 15);
        int k2 = ms & 31;
        float a = w128 * (float)((q * k2) & 127);
        float c = cosf(a), s = sinf(a);
        const float s4 = 1.0f / 67108864.0f;  // (1/64)*(1/16384)*(1/64)
        v = ((ms < 32) ? (c + s) : (c - s)) * s4;
    } else if (idx < 102400) {
        // T3f: frag=(nt*2+hl); B[k][n]=T3[k=8*(l/16)+i][j=nt*16+l%16]
        int t = idx - 98304;
        int frag = t >> 9, lane = (t >> 3) & 63, ii = t & 7;
        hl = frag & 1;
        int nt = frag >> 1;
        int k = (lane >> 4) * 8 + ii;
        int j = nt * 16 + (lane & 15);
        int jj = j & 31;
        float a = w32 * (float)((jj * k) & 31);
        v = (j < 32) ? cosf(a) : sinf(a);
    } else {
        // T4f: frag=((mt*2+ks)*2+hl); A[k1][m]=T4t[m=ks*32+8*(l/16)+i][k1=mt*16+l%16]
        int t = idx - 102400;
        int frag = t >> 9, lane = (t >> 3) & 63, ii = t & 7;
        hl = frag & 1;
        int ks = (frag >> 1) & 1, mt = frag >> 2;
        int m = ks * 32 + (lane >> 4) * 8 + ii;
        int k1 = mt * 16 + (lane & 15);
        if (m < 32) { float a = w32 * (float)((k1 * m) & 31); v = cosf(a) + sinf(a); }
        else { int mm = m - 32; float a = w32 * (float)((k1 * mm) & 31); v = cosf(a) - sinf(a); }
        v *= (1.0f / 1024.0f);
    }
    unsigned short h = f2bf(v);
    tf[idx] = hl ? f2bf(v - bf2f(h)) : h;
}

// ---------------- Fused kernel: one block = one channel, end-to-end ----------------
__global__ __launch_bounds__(256) void kFused(const float* __restrict__ x,
                                              const float* __restrict__ w1,
                                              const float* __restrict__ w2,
                                              float* __restrict__ out,
                                              const float* __restrict__ ws) {
    // Phase-overlaid LDS union; liveness separated by __syncthreads (see timeline).
    __shared__ __align__(16) unsigned char smem[61440];
    const int tid  = threadIdx.x;
    const int lane = tid & 63;
    const int wv   = tid >> 6;           // 4 waves
    const int ch   = blockIdx.x;
    const int lr = lane & 15;            // row-in-tile (A) / col-in-tile (B,C)
    const int lk = (lane >> 4) * 8;      // k-offset within 32-slice
    const int lq = (lane >> 4) * 4;      // C/D row group
    const float* xg = x + ch * 16384;

    const bf16x8* tfv = (const bf16x8*)ws;   // frag stride = 64 bf16x8
    const bf16x8* t1f = tfv;                 // 32 frags
    const bf16x8* t2f = tfv + 32 * 64;       // 64 frags
    const bf16x8* t5f = tfv + 96 * 64;       // 64 frags
    const bf16x8* t6f = tfv + 160 * 64;      // 32 frags
    const bf16x8* t3f = tfv + 192 * 64;      // 8 frags
    const bf16x8* t4f = tfv + 200 * 64;      // 8 frags

    // prefetch weight tiles (used in phase B staging)
    float4 wl1 = *(const float4*)(w1 + ch * 1024 + tid * 4);
    float4 wl2 = *(const float4*)(w2 + ch * 1024 + tid * 4);

    const f32x4 zero4 = {0.f, 0.f, 0.f, 0.f};

    // ================= A1: CS = x(128x128) . T1(128x64) =================
    unsigned short* CSThi = (unsigned short*)smem;            // [64][136]
    unsigned short* CSTlo = (unsigned short*)(smem + 17408);
    {
        f32x4 acc[2][4];
#pragma unroll
        for (int mt = 0; mt < 2; mt++)
#pragma unroll
            for (int nt = 0; nt < 4; nt++) acc[mt][nt] = zero4;
#pragma unroll
        for (int ks = 0; ks < 4; ks++) {
            bf16x8 ah[2], al[2];
#pragma unroll
            for (int mt = 0; mt < 2; mt++) {
                const float* src = xg + (wv * 32 + mt * 16 + lr) * 128 + ks * 32 + lk;
                float4 u0 = *(const float4*)src;
                float4 u1 = *(const float4*)(src + 4);
                float av[8] = {u0.x, u0.y, u0.z, u0.w, u1.x, u1.y, u1.z, u1.w};
#pragma unroll
                for (int i = 0; i < 8; i++) {
                    unsigned short h = f2bf(av[i]);
                    ah[mt][i] = (short)h;
                    al[mt][i] = (short)f2bf(av[i] - bf2f(h));
                }
            }
#pragma unroll
            for (int nt = 0; nt < 4; nt++) {
                bf16x8 bh = t1f[((ks * 4 + nt) * 2 + 0) * 64 + lane];
                bf16x8 bl = t1f[((ks * 4 + nt) * 2 + 1) * 64 + lane];
#pragma unroll
                for (int mt = 0; mt < 2; mt++) {
                    acc[mt][nt] = __builtin_amdgcn_mfma_f32_16x16x32_bf16(ah[mt], bh, acc[mt][nt], 0, 0, 0);
                    acc[mt][nt] = __builtin_amdgcn_mfma_f32_16x16x32_bf16(ah[mt], bl, acc[mt][nt], 0, 0, 0);
                    acc[mt][nt] = __builtin_amdgcn_mfma_f32_16x16x32_bf16(al[mt], bh, acc[mt][nt], 0, 0, 0);
                }
            }
        }
        // CS -> CST (transposed) bf16 hi/lo
#pragma unroll
        for (int mt = 0; mt < 2; mt++)
#pragma unroll
            for (int nt = 0; nt < 4; nt++) {
                const int j  = nt * 16 + lr;
                const int n1 = wv * 32 + mt * 16 + lq;
                uint2 hv, lv;
                pack4(acc[mt][nt], &hv, &lv);
                *(uint2*)&CSThi[j * 136 + n1] = hv;
                *(uint2*)&CSTlo[j * 136 + n1] = lv;
            }
    }
    __syncthreads();  // s1: CST ready

    // ================= A2: Xc = T2t^T(64x256) . stack(CS) =================
    f32x4 a2[2] = {zero4, zero4};
#pragma unroll
    for (int ks = 0; ks < 8; ks++) {
        bf16x8 ah = t2f[((wv * 8 + ks) * 2 + 0) * 64 + lane];
        bf16x8 al = t2f[((wv * 8 + ks) * 2 + 1) * 64 + lane];
        const int colb = (ks & 3) * 32 + lk;
        const int rofs = (ks >= 4) ? 32 : 0;
#pragma unroll
        for (int nt = 0; nt < 2; nt++) {
            const int row = nt * 16 + lr + rofs;
            bf16x8 bh = *(const bf16x8*)&CSThi[row * 136 + colb];
            bf16x8 bl = *(const bf16x8*)&CSTlo[row * 136 + colb];
            a2[nt] = __builtin_amdgcn_mfma_f32_16x16x32_bf16(ah, bh, a2[nt], 0, 0, 0);
            a2[nt] = __builtin_amdgcn_mfma_f32_16x16x32_bf16(ah, bl, a2[nt], 0, 0, 0);
            a2[nt] = __builtin_amdgcn_mfma_f32_16x16x32_bf16(al, bh, a2[nt], 0, 0, 0);
        }
    }
    __syncthreads();  // s2: CST reads done; region reusable

    // ========== stage tiles for B: XCF[4][32][40] hi/lo (row-major A-frag layout) ==========
    // tiles: 0 = crop0 (Xc rows 0..31), 1 = crop1, 2 = w1, 3 = w2
    unsigned short* XCFhi = (unsigned short*)smem;            // [4][32][40]
    unsigned short* XCFlo = (unsigned short*)(smem + 10240);
    {
        const int c  = wv >> 1;                   // crop tile of this wave's Xc rows
        const int nb = (wv & 1) * 16 + lq;        // n1 base
#pragma unroll
        for (int nt = 0; nt < 2; nt++)
#pragma unroll
            for (int r = 0; r < 4; r++) {
                float v = a2[nt][r];
                unsigned short h = f2bf(v);
                XCFhi[c * 1280 + (nb + r) * 40 + nt * 16 + lr] = h;
                XCFlo[c * 1280 + (nb + r) * 40 + nt * 16 + lr] = f2bf(v - bf2f(h));
            }
        // weights: thread tid covers row rw = tid>>3, cols cw..cw+3 of both w tiles
        const int rw = tid >> 3, cw = (tid & 7) * 4;
        float a1v[4] = {wl1.x, wl1.y, wl1.z, wl1.w};
        float a2v[4] = {wl2.x, wl2.y, wl2.z, wl2.w};
        unsigned short h1[4], l1[4], h2[4], l2[4];
#pragma unroll
        for (int i = 0; i < 4; i++) {
            h1[i] = f2bf(a1v[i]); l1[i] = f2bf(a1v[i] - bf2f(h1[i]));
            h2[i] = f2bf(a2v[i]); l2[i] = f2bf(a2v[i] - bf2f(h2[i]));
        }
        *(uint2*)&XCFhi[2 * 1280 + rw * 40 + cw] =
            make_uint2((unsigned int)h1[0] | ((unsigned int)h1[1] << 16),
                       (unsigned int)h1[2] | ((unsigned int)h1[3] << 16));
        *(uint2*)&XCFlo[2 * 1280 + rw * 40 + cw] =
            make_uint2((unsigned int)l1[0] | ((unsigned int)l1[1] << 16),
                       (unsigned int)l1[2] | ((unsigned int)l1[3] << 16));
        *(uint2*)&XCFhi[3 * 1280 + rw * 40 + cw] =
            make_uint2((unsigned int)h2[0] | ((unsigned int)h2[1] << 16),
                       (unsigned int)h2[2] | ((unsigned int)h2[3] << 16));
        *(uint2*)&XCFlo[3 * 1280 + rw * 40 + cw] =
            make_uint2((unsigned int)l2[0] | ((unsigned int)l2[1] << 16),
                       (unsigned int)l2[2] | ((unsigned int)l2[3] << 16));
    }
    __syncthreads();  // s3: XCF ready

    // ================= B1 stage i: G_t = tile_t . T3  (wave wv -> tile wv) =================
    unsigned short* GThi = (unsigned short*)(smem + 20480);   // [4][64][40] (GT[j][n1])
    unsigned short* GTlo = (unsigned short*)(smem + 40960);
    {
        const int t = wv;
        f32x4 g[2][4];
#pragma unroll
        for (int mt = 0; mt < 2; mt++)
#pragma unroll
            for (int nt = 0; nt < 4; nt++) g[mt][nt] = zero4;
        bf16x8 ah[2], al[2];
#pragma unroll
        for (int mt = 0; mt < 2; mt++) {
            ah[mt] = *(const bf16x8*)&XCFhi[t * 1280 + (mt * 16 + lr) * 40 + lk];
            al[mt] = *(const bf16x8*)&XCFlo[t * 1280 + (mt * 16 + lr) * 40 + lk];
        }
#pragma unroll
        for (int nt = 0; nt < 4; nt++) {
            bf16x8 bh = t3f[(nt * 2 + 0) * 64 + lane];
            bf16x8 bl = t3f[(nt * 2 + 1) * 64 + lane];
#pragma unroll
            for (int mt = 0; mt < 2; mt++) {
                g[mt][nt] = __builtin_amdgcn_mfma_f32_16x16x32_bf16(ah[mt], bh, g[mt][nt], 0, 0, 0);
                g[mt][nt] = __builtin_amdgcn_mfma_f32_16x16x32_bf16(ah[mt], bl, g[mt][nt], 0, 0, 0);
                g[mt][nt] = __builtin_amdgcn_mfma_f32_16x16x32_bf16(al[mt], bh, g[mt][nt], 0, 0, 0);
            }
        }
#pragma unroll
        for (int mt = 0; mt < 2; mt++)
#pragma unroll
            for (int nt = 0; nt < 4; nt++) {
                const int j = nt * 16 + lr, n1b = mt * 16 + lq;
                uint2 hv, lv;
                pack4(g[mt][nt], &hv, &lv);
                *(uint2*)&GThi[t * 2560 + j * 40 + n1b] = hv;
                *(uint2*)&GTlo[t * 2560 + j * 40 + n1b] = lv;
            }
    }
    __syncthreads();  // s4: GT ready; XCF dead

    // ================= B1 stage ii: hat_t = T4t^T . stack(G_t) =================
    float* HAT = (float*)smem;                                // [4][32][36] f32
    {
        const int t = wv;
        f32x4 hacc[2][2];
#pragma unroll
        for (int mt = 0; mt < 2; mt++)
#pragma unroll
            for (int nt = 0; nt < 2; nt++) hacc[mt][nt] = zero4;
#pragma unroll
        for (int ks = 0; ks < 2; ks++) {
#pragma unroll
            for (int mt = 0; mt < 2; mt++) {
                bf16x8 ah = t4f[((mt * 2 + ks) * 2 + 0) * 64 + lane];
                bf16x8 al = t4f[((mt * 2 + ks) * 2 + 1) * 64 + lane];
#pragma unroll
                for (int nt = 0; nt < 2; nt++) {
                    const int row = nt * 16 + lr + 32 * ks;
                    bf16x8 bh = *(const bf16x8*)&GThi[t * 2560 + row * 40 + lk];
                    bf16x8 bl = *(const bf16x8*)&GTlo[t * 2560 + row * 40 + lk];
                    hacc[mt][nt] = __builtin_amdgcn_mfma_f32_16x16x32_bf16(ah, bh, hacc[mt][nt], 0, 0, 0);
                    hacc[mt][nt] = __builtin_amdgcn_mfma_f32_16x16x32_bf16(ah, bl, hacc[mt][nt], 0, 0, 0);
                    hacc[mt][nt] = __builtin_amdgcn_mfma_f32_16x16x32_bf16(al, bh, hacc[mt][nt], 0, 0, 0);
                }
            }
        }
        __syncthreads();  // s5a: GT reads done before HAT overwrites XCF region? (HAT=[0,18432) vs GT=[20480,..): disjoint; this sync orders HAT write after all XCF reads -- already done at s4. Kept for GT->GT2 reuse safety below.
#pragma unroll
        for (int mt = 0; mt < 2; mt++)
#pragma unroll
            for (int nt = 0; nt < 2; nt++)
#pragma unroll
                for (int r = 0; r < 4; r++)
                    HAT[t * 1152 + (mt * 16 + lq + r) * 36 + nt * 16 + lr] = hacc[mt][nt][r];
    }
    __syncthreads();  // s5: HAT ready; GT dead

    // ========= B2 stage i: G'_t = (hatX_t * hatW_t) . T3  (wave -> tile wv>>1, half wv&1) =========
    unsigned short* GT2hi = (unsigned short*)(smem + 20480);  // [2][64][40]
    unsigned short* GT2lo = (unsigned short*)(smem + 30720);
    {
        const int t = wv >> 1, h = wv & 1;
        const int n1 = h * 16 + lr;
        float pv[8];
#pragma unroll
        for (int i = 0; i < 8; i++) {
            float px = HAT[t * 1152 + n1 * 36 + lk + i];
            float pw = HAT[(t + 2) * 1152 + n1 * 36 + lk + i];
            pv[i] = px * pw;
        }
        bf16x8 ah, al;
#pragma unroll
        for (int i = 0; i < 8; i++) {
            unsigned short hh = f2bf(pv[i]);
            ah[i] = (short)hh;
            al[i] = (short)f2bf(pv[i] - bf2f(hh));
        }
        f32x4 g[4];
#pragma unroll
        for (int nt = 0; nt < 4; nt++) g[nt] = zero4;
#pragma unroll
        for (int nt = 0; nt < 4; nt++) {
            bf16x8 bh = t3f[(nt * 2 + 0) * 64 + lane];
            bf16x8 bl = t3f[(nt * 2 + 1) * 64 + lane];
            g[nt] = __builtin_amdgcn_mfma_f32_16x16x32_bf16(ah, bh, g[nt], 0, 0, 0);
            g[nt] = __builtin_amdgcn_mfma_f32_16x16x32_bf16(ah, bl, g[nt], 0, 0, 0);
            g[nt] = __builtin_amdgcn_mfma_f32_16x16x32_bf16(al, bh, g[nt], 0, 0, 0);
        }
#pragma unroll
        for (int nt = 0; nt < 4; nt++) {
            const int j = nt * 16 + lr, n1b = h * 16 + lq;
            uint2 hv, lv;
            pack4(g[nt], &hv, &lv);
            *(uint2*)&GT2hi[t * 2560 + j * 40 + n1b] = hv;
            *(uint2*)&GT2lo[t * 2560 + j * 40 + n1b] = lv;
        }
    }
    __syncthreads();  // s6: GT2 ready; HAT dead after reads above

    // ========= B2 stage ii: Y_t = T4t^T . stack(G'_t) -> YT[k2][j]  (j = t*32 + k1) =========
    unsigned short* YThi = (unsigned short*)smem;             // [32][72]
    unsigned short* YTlo = (unsigned short*)(smem + 4608);
    {
        const int t = wv >> 1, h = wv & 1;
        f32x4 ya[2] = {zero4, zero4};
#pragma unroll
        for (int ks = 0; ks < 2; ks++) {
            bf16x8 ah = t4f[((h * 2 + ks) * 2 + 0) * 64 + lane];
            bf16x8 al = t4f[((h * 2 + ks) * 2 + 1) * 64 + lane];
#pragma unroll
            for (int nt = 0; nt < 2; nt++) {
                const int row = nt * 16 + lr + 32 * ks;
                bf16x8 bh = *(const bf16x8*)&GT2hi[t * 2560 + row * 40 + lk];
                bf16x8 bl = *(const bf16x8*)&GT2lo[t * 2560 + row * 40 + lk];
                ya[nt] = __builtin_amdgcn_mfma_f32_16x16x32_bf16(ah, bh, ya[nt], 0, 0, 0);
                ya[nt] = __builtin_amdgcn_mfma_f32_16x16x32_bf16(ah, bl, ya[nt], 0, 0, 0);
                ya[nt] = __builtin_amdgcn_mfma_f32_16x16x32_bf16(al, bh, ya[nt], 0, 0, 0);
            }
        }
        __syncthreads();  // s7a: HAT/YT region reads fully done before YT write (YT overlaps HAT)
#pragma unroll
        for (int nt = 0; nt < 2; nt++) {
            const int k2 = nt * 16 + lr;
            const int j0 = t * 32 + h * 16 + lq;
            uint2 hv, lv;
            pack4(ya[nt], &hv, &lv);
            *(uint2*)&YThi[k2 * 72 + j0] = hv;
            *(uint2*)&YTlo[k2 * 72 + j0] = lv;
        }
    }
    __syncthreads();  // s7: YT ready; GT2 dead

    // ================= C1: UVT(32x256) = Yt(32x64) . T5(64x256) -> WT[p][ms] =================
    unsigned short* WThi = (unsigned short*)(smem + 9216);    // [128][72]
    unsigned short* WTlo = (unsigned short*)(smem + 27648);
    {
        f32x4 acc1[2][4];
#pragma unroll
        for (int mt = 0; mt < 2; mt++)
#pragma unroll
            for (int n = 0; n < 4; n++) acc1[mt][n] = zero4;
        bf16x8 yh[2][2], yl[2][2];
#pragma unroll
        for (int mt = 0; mt < 2; mt++)
#pragma unroll
            for (int ks = 0; ks < 2; ks++) {
                yh[mt][ks] = *(const bf16x8*)&YThi[(mt * 16 + lr) * 72 + ks * 32 + lk];
                yl[mt][ks] = *(const bf16x8*)&YTlo[(mt * 16 + lr) * 72 + ks * 32 + lk];
            }
#pragma unroll
        for (int ks = 0; ks < 2; ks++)
#pragma unroll
            for (int ntl = 0; ntl < 4; ntl++) {
                const int nt = wv * 4 + ntl;
                bf16x8 bh = t5f[((ks * 16 + nt) * 2 + 0) * 64 + lane];
                bf16x8 bl = t5f[((ks * 16 + nt) * 2 + 1) * 64 + lane];
#pragma unroll
                for (int mt = 0; mt < 2; mt++) {
                    acc1[mt][ntl] = __builtin_amdgcn_mfma_f32_16x16x32_bf16(yh[mt][ks], bh, acc1[mt][ntl], 0, 0, 0);
                    acc1[mt][ntl] = __builtin_amdgcn_mfma_f32_16x16x32_bf16(yh[mt][ks], bl, acc1[mt][ntl], 0, 0, 0);
                    acc1[mt][ntl] = __builtin_amdgcn_mfma_f32_16x16x32_bf16(yl[mt][ks], bh, acc1[mt][ntl], 0, 0, 0);
                }
            }
        // UVT -> WT: (k2 = mt*16+lq+rr, r = nt*16+lr); p = r%128, ms = k2 + 32*(r>=128)
#pragma unroll
        for (int mt = 0; mt < 2; mt++)
#pragma unroll
            for (int ntl = 0; ntl < 4; ntl++) {
                const int nt = wv * 4 + ntl;
                const int p = (nt & 7) * 16 + lr;
                const int ms0 = ((nt >= 8) ? 32 : 0) + mt * 16 + lq;
                uint2 hv, lv;
                pack4(acc1[mt][ntl], &hv, &lv);
                *(uint2*)&WThi[p * 72 + ms0] = hv;
                *(uint2*)&WTlo[p * 72 + ms0] = lv;
            }
    }
    __syncthreads();  // s8: WT ready

    // ================= C2: out(128x128) = WT(128x64) . T6(64x128) =================
    {
        bf16x8 wth[2][2], wtl[2][2];
#pragma unroll
        for (int mtl = 0; mtl < 2; mtl++)
#pragma unroll
            for (int ks = 0; ks < 2; ks++) {
                const int row = (wv * 2 + mtl) * 16 + lr;
                wth[mtl][ks] = *(const bf16x8*)&WThi[row * 72 + ks * 32 + lk];
                wtl[mtl][ks] = *(const bf16x8*)&WTlo[row * 72 + ks * 32 + lk];
            }
        f32x4 acc2[2][8];
#pragma unroll
        for (int mtl = 0; mtl < 2; mtl++)
#pragma unroll
            for (int n = 0; n < 8; n++) acc2[mtl][n] = zero4;
#pragma unroll
        for (int ks = 0; ks < 2; ks++)
#pragma unroll
            for (int nt = 0; nt < 8; nt++) {
                bf16x8 bh = t6f[((ks * 8 + nt) * 2 + 0) * 64 + lane];
                bf16x8 bl = t6f[((ks * 8 + nt) * 2 + 1) * 64 + lane];
#pragma unroll
                for (int mtl = 0; mtl < 2; mtl++) {
                    acc2[mtl][nt] = __builtin_amdgcn_mfma_f32_16x16x32_bf16(wth[mtl][ks], bh, acc2[mtl][nt], 0, 0, 0);
                    acc2[mtl][nt] = __builtin_amdgcn_mfma_f32_16x16x32_bf16(wth[mtl][ks], bl, acc2[mtl][nt], 0, 0, 0);
                    acc2[mtl][nt] = __builtin_amdgcn_mfma_f32_16x16x32_bf16(wtl[mtl][ks], bh, acc2[mtl][nt], 0, 0, 0);
                }
            }
        float* og = out + ch * 16384;
#pragma unroll
        for (int mtl = 0; mtl < 2; mtl++) {
            const int pb = (wv * 2 + mtl) * 16 + lq;
#pragma unroll
            for (int nt = 0; nt < 8; nt++)
#pragma unroll
                for (int r = 0; r < 4; r++)
                    og[(pb + r) * 128 + nt * 16 + lr] = acc2[mtl][nt][r];
        }
    }
}

extern "C" void kernel_launch(void* const* d_in, const int* in_sizes, int n_in,
                              void* d_out, int out_size, void* d_ws, size_t ws_size,
                              hipStream_t stream) {
    (void)in_sizes; (void)n_in; (void)out_size;
    if (ws_size < (size_t)WS_FLOATS * sizeof(float)) return;  // tables only (~208 KB)
    const float* x  = (const float*)d_in[0];
    const float* w1 = (const float*)d_in[1];
    const float* w2 = (const float*)d_in[2];
    float* out = (float*)d_out;
    float* ws  = (float*)d_ws;

    hipLaunchKernelGGL(init_frag, dim3(416), dim3(256), 0, stream, ws);
    hipLaunchKernelGGL(kFused, dim3(4096), dim3(256), 0, stream, x, w1, w2, out, ws);
}